// Round 2
// baseline (913.221 us; speedup 1.0000x reference)
//
#include <hip/hip_runtime.h>
#include <hip/hip_bf16.h>
#include <stdint.h>

#define NVOX 131072
#define CCH  128
#define EPSV 1e-4f

typedef __bf16 bf16_t;
typedef bf16_t bf16x8 __attribute__((ext_vector_type(8)));
typedef bf16_t bf16x4 __attribute__((ext_vector_type(4)));
typedef float  f32x4  __attribute__((ext_vector_type(4)));

__device__ __forceinline__ void async16(void* lds, const void* g) {
    __builtin_amdgcn_global_load_lds(
        (const __attribute__((address_space(1))) uint32_t*)g,
        (__attribute__((address_space(3))) uint32_t*)lds, 16, 0, 0);
}

// ---------- prep: features f32 -> bf16 ----------
__global__ void k_prep_feat(const float* __restrict__ f, bf16_t* __restrict__ fb) {
    int i = blockIdx.x * 256 + threadIdx.x;      // over N*C/4 = 4194304
    const float4* f4 = (const float4*)f;
    float4 v = f4[i];
    bf16x4 o;
    o[0] = (bf16_t)v.x; o[1] = (bf16_t)v.y; o[2] = (bf16_t)v.z; o[3] = (bf16_t)v.w;
    ((bf16x4*)fb)[i] = o;
}

// ---------- prep: zero pad rows + stats ----------
__global__ void k_prep_misc(bf16_t* featb, bf16_t* y1, bf16_t* y2, float* stats) {
    int t = threadIdx.x;
    if (t < 128) {
        featb[(size_t)NVOX * CCH + t] = (bf16_t)0.0f;
        y1[(size_t)NVOX * CCH + t]    = (bf16_t)0.0f;
        y2[(size_t)NVOX * CCH + t]    = (bf16_t)0.0f;
    }
    for (int i = t; i < 768; i += 256) stats[i] = 0.0f;
}

// ---------- prep: W [27,Ci,Co] f32 -> W^T [layer][k][co][ci] bf16 ----------
__global__ void k_prep_w(const float* __restrict__ w0, const float* __restrict__ w1,
                         const float* __restrict__ w2, bf16_t* __restrict__ wbt) {
    int blk = blockIdx.x;                // 0..80
    int layer = blk / 27, k = blk % 27;
    const float* w = (layer == 0 ? w0 : (layer == 1 ? w1 : w2)) + k * 16384;
    __shared__ bf16_t tile[128][132];
    for (int e = threadIdx.x; e < 16384; e += 256) {
        int ci = e >> 7, co = e & 127;
        tile[co][ci] = (bf16_t)w[e];
    }
    __syncthreads();
    bf16_t* out = wbt + (size_t)blk * 16384;
    for (int e = threadIdx.x; e < 16384; e += 256) {
        int co = e >> 7, ci = e & 127;
        out[e] = tile[co][ci];
    }
}

// ---------- prep: rulebook per (block of 128 rows, tap k) ----------
// entry = (local_row << 18) | gather_idx ; pad entries = NVOX (zero row, discarded)
__global__ void k_prep_rule(const int* __restrict__ nbr, unsigned* __restrict__ rule,
                            int* __restrict__ cntTab) {
    __shared__ int snbr[128 * 27];       // 13.5KB
    __shared__ int c0s[4];
    const int b = blockIdx.x, tid = threadIdx.x, m0 = b << 7;
    for (int i = tid; i < 128 * 27; i += 256) snbr[i] = nbr[(size_t)m0 * 27 + i];
    __syncthreads();
    const int w = tid >> 6, l = tid & 63;
    for (int k = 0; k < 27; ++k) {
        int idx = 0; bool valid = false;
        if (tid < 128) { idx = snbr[tid * 27 + k]; valid = idx >= 0; }
        unsigned long long m = __ballot(valid);
        if (l == 0) c0s[w] = (int)__popcll(m);
        __syncthreads();
        int base = (w == 1) ? c0s[0] : 0;
        int total = c0s[0] + c0s[1];
        int prefix = (int)__popcll(m & ((1ull << l) - 1ull));
        unsigned* rk = rule + ((size_t)b * 27 + k) * 128;
        if (valid) rk[base + prefix] = ((unsigned)tid << 18) | (unsigned)idx;
        int nr = ((total + 15) >> 4) << 4;
        if (tid < nr - total) rk[total + tid] = (unsigned)NVOX;   // pad
        if (tid == 0) cntTab[b * 27 + k] = total;
        __syncthreads();
    }
}

// ---------- sparse conv: rulebook gather-GEMM, LDS f32 accumulator ----------
__global__ __launch_bounds__(512, 1) void k_conv_sp(
        const bf16_t* __restrict__ xin,     // (N+1) x 128 bf16
        const bf16_t* __restrict__ wbt,     // 27 x 128co x 128ci bf16
        const unsigned* __restrict__ rule,  // [1024][27][128]
        const int* __restrict__ cntTab,     // [1024][27]
        bf16_t* __restrict__ yout,          // N x 128 bf16
        float* __restrict__ stat)           // [0..127]=sum [128..255]=sumsq
{
    __shared__ __align__(16) float  accf[128 * 128];     // 64KB
    __shared__ __align__(16) bf16_t smB[128 * 128];      // 32KB (swizzled slots)
    __shared__ __align__(16) bf16_t smA[128 * 128];      // 32KB (swizzled slots)
    __shared__ unsigned short rowLds[128];
    __shared__ float ssum[128], ssq[128];

    const int tid = threadIdx.x;
    const int b = blockIdx.x;
    const int w = tid >> 6, l = tid & 63;
    const int lrow = l & 15, lq = l >> 4;

    for (int i = tid; i < 128 * 128 / 4; i += 512)
        ((f32x4*)accf)[i] = (f32x4){0.f, 0.f, 0.f, 0.f};
    if (tid < 128) { ssum[tid] = 0.f; ssq[tid] = 0.f; }

    const char* xb = (const char*)xin;
    const unsigned* ruleB = rule + (size_t)b * 27 * 128;

    for (int k = 0; k < 27; ++k) {
        const int cnt = cntTab[b * 27 + k];
        if (cnt == 0) continue;
        const int ntiles = (cnt + 15) >> 4;
        const int nchunks = ntiles << 8;            // ntiles*16 rows * 16 chunks

        __syncthreads();   // protect smA/smB/rowLds from previous iteration readers

        // stage B_k: 32KB, 2048 16B-chunks, XOR-swizzled within each 256B row
        const char* wk = (const char*)wbt + ((size_t)k << 15);
        #pragma unroll
        for (int r = 0; r < 4; ++r) {
            int c = (r << 9) + tid;
            int row = c >> 4, s = c & 15;
            int sg = s ^ (row & 15);
            async16((char*)smB + ((size_t)c << 4), wk + (row << 8) + (sg << 4));
        }
        // stage A: compacted rows, same swizzle
        const unsigned* rk = ruleB + (k << 7);
        for (int c0 = 0; c0 < nchunks; c0 += 512) {
            if ((c0 + (w << 6)) < nchunks) {        // wave-uniform guard
                int c = c0 + tid;
                int row = c >> 4, s = c & 15;
                unsigned e = rk[row];
                unsigned gidx = e & 0x3FFFFu;
                int sg = s ^ (row & 15);
                async16((char*)smA + ((size_t)c << 4),
                        xb + ((size_t)gidx << 8) + (sg << 4));
                if (s == 0) rowLds[row] = (unsigned short)(e >> 18);
            }
        }
        __syncthreads();

        // compute: wave w owns cols [w*16, w*16+16)
        bf16x8 bfr[4];
        #pragma unroll
        for (int c = 0; c < 4; ++c) {
            int slot = ((c << 2) + lq) ^ lrow;
            bfr[c] = *(const bf16x8*)((const char*)smB +
                      (((w << 4) + lrow) << 8) + (slot << 4));
        }
        f32x4 tacc[8];
        #pragma unroll
        for (int t = 0; t < 8; ++t) {
            if (t < ntiles) {
                f32x4 a = {0.f, 0.f, 0.f, 0.f};
                #pragma unroll
                for (int c = 0; c < 4; ++c) {
                    int slot = ((c << 2) + lq) ^ lrow;
                    bf16x8 af = *(const bf16x8*)((const char*)smA +
                                 (((t << 4) + lrow) << 8) + (slot << 4));
                    a = __builtin_amdgcn_mfma_f32_16x16x32_bf16(af, bfr[c], a, 0, 0, 0);
                }
                tacc[t] = a;
            }
        }
        // scatter-add into LDS accumulator (cols disjoint per wave -> no races)
        const int col = (w << 4) + lrow;
        #pragma unroll
        for (int t = 0; t < 8; ++t) {
            if (t < ntiles) {
                #pragma unroll
                for (int r = 0; r < 4; ++r) {
                    int ridx = (t << 4) + (lq << 2) + r;
                    if (ridx < cnt) {
                        int row = rowLds[ridx];
                        accf[(row << 7) + col] += tacc[t][r];
                    }
                }
            }
        }
    }
    __syncthreads();

    // epilogue: bf16 store + channel stats
    float ps[8] = {0,0,0,0,0,0,0,0}, pq[8] = {0,0,0,0,0,0,0,0};
    const int cb = (tid & 15) << 3;
    bf16_t* yrow = yout + ((size_t)b << 7) * CCH;
    #pragma unroll
    for (int r = 0; r < 4; ++r) {
        int row = (r << 5) + (tid >> 4);
        const float* ap = accf + (row << 7) + cb;
        bf16x8 o;
        #pragma unroll
        for (int i = 0; i < 8; ++i) {
            float v = ap[i];
            o[i] = (bf16_t)v;
            ps[i] += v; pq[i] += v * v;
        }
        ((bf16x8*)yrow)[(row << 4) + (tid & 15)] = o;
    }
    #pragma unroll
    for (int i = 0; i < 8; ++i) {
        ps[i] += __shfl_xor(ps[i], 16, 64);
        ps[i] += __shfl_xor(ps[i], 32, 64);
        pq[i] += __shfl_xor(pq[i], 16, 64);
        pq[i] += __shfl_xor(pq[i], 32, 64);
    }
    if (lq == 0) {
        #pragma unroll
        for (int i = 0; i < 8; ++i) {
            atomicAdd(&ssum[cb + i], ps[i]);
            atomicAdd(&ssq[cb + i],  pq[i]);
        }
    }
    __syncthreads();
    if (tid < 128) {
        atomicAdd(&stat[tid],       ssum[tid]);
        atomicAdd(&stat[128 + tid], ssq[tid]);
    }
}

// ---------- BN + LeakyReLU, bf16 in -> bf16 out (in-place safe) ----------
__global__ void k_bnact(const bf16_t* __restrict__ x, const float* __restrict__ stat,
                        const float* __restrict__ g, const float* __restrict__ b,
                        bf16_t* __restrict__ out, float slope) {
    __shared__ float sc[128], sh[128];
    int tid = threadIdx.x;
    if (tid < 128) {
        float mu  = stat[tid] * (1.0f / NVOX);
        float var = stat[128 + tid] * (1.0f / NVOX) - mu * mu;
        float inv = rsqrtf(var + EPSV);
        float s = g[tid] * inv;
        sc[tid] = s;
        sh[tid] = b[tid] - mu * s;
    }
    __syncthreads();
    int i = blockIdx.x * 256 + tid;              // over N*C/8 = 2097152
    bf16x8 v = ((const bf16x8*)x)[i];
    int c = (i << 3) & 127;
    bf16x8 o;
    #pragma unroll
    for (int j = 0; j < 8; ++j) {
        float y = (float)v[j] * sc[c + j] + sh[c + j];
        y = y >= 0.0f ? y : slope * y;
        o[j] = (bf16_t)y;
    }
    ((bf16x8*)out)[i] = o;
}

// ---------- BN3 + residual + LeakyReLU(1/3) -> f32 d_out ----------
__global__ void k_final(const bf16_t* __restrict__ x, const float* __restrict__ stat,
                        const float* __restrict__ g, const float* __restrict__ b,
                        const bf16_t* __restrict__ res, float* __restrict__ out) {
    __shared__ float sc[128], sh[128];
    int tid = threadIdx.x;
    if (tid < 128) {
        float mu  = stat[tid] * (1.0f / NVOX);
        float var = stat[128 + tid] * (1.0f / NVOX) - mu * mu;
        float inv = rsqrtf(var + EPSV);
        float s = g[tid] * inv;
        sc[tid] = s;
        sh[tid] = b[tid] - mu * s;
    }
    __syncthreads();
    int i = blockIdx.x * 256 + tid;              // over N*C/8
    bf16x8 v = ((const bf16x8*)x)[i];
    bf16x8 r8 = ((const bf16x8*)res)[i];
    int c = (i << 3) & 127;
    const float k3 = 1.0f / 3.0f;
    float4 o0, o1;
    float* op = (float*)&o0;
    #pragma unroll
    for (int j = 0; j < 8; ++j) {
        float y = (float)v[j] * sc[c + j] + sh[c + j] + (float)r8[j];
        y = y >= 0.0f ? y : k3 * y;
        if (j < 4) ((float*)&o0)[j] = y; else ((float*)&o1)[j - 4] = y;
    }
    (void)op;
    ((float4*)out)[2 * i]     = o0;
    ((float4*)out)[2 * i + 1] = o1;
}

extern "C" void kernel_launch(void* const* d_in, const int* in_sizes, int n_in,
                              void* d_out, int out_size, void* d_ws, size_t ws_size,
                              hipStream_t stream) {
    (void)in_sizes; (void)n_in; (void)out_size; (void)ws_size;
    const float* features = (const float*)d_in[0];
    const int*   nbr      = (const int*)d_in[1];
    const float* w1 = (const float*)d_in[2];
    const float* w2 = (const float*)d_in[3];
    const float* w3 = (const float*)d_in[4];
    const float* g1 = (const float*)d_in[5];
    const float* b1 = (const float*)d_in[6];
    const float* g2 = (const float*)d_in[7];
    const float* b2 = (const float*)d_in[8];
    const float* g3 = (const float*)d_in[9];
    const float* b3 = (const float*)d_in[10];

    char* ws = (char*)d_ws;
    const size_t SZ_FB = (size_t)(NVOX + 1) * CCH * 2;   // 33,554,688 B
    bf16_t*   featb  = (bf16_t*)(ws);
    bf16_t*   y1     = (bf16_t*)(ws + SZ_FB);
    bf16_t*   y2     = (bf16_t*)(ws + 2 * SZ_FB);
    bf16_t*   y3     = (bf16_t*)(ws + 3 * SZ_FB);
    bf16_t*   wbt    = (bf16_t*)(ws + 4 * SZ_FB);
    unsigned* rule   = (unsigned*)(ws + 4 * SZ_FB + 2654208);
    int*      cntTab = (int*)(ws + 4 * SZ_FB + 2654208 + 14155776);
    float*    stats  = (float*)(ws + 4 * SZ_FB + 2654208 + 14155776 + 110592);

    k_prep_feat<<<16384, 256, 0, stream>>>(features, featb);
    k_prep_misc<<<1, 256, 0, stream>>>(featb, y1, y2, stats);
    k_prep_w<<<81, 256, 0, stream>>>(w1, w2, w3, wbt);
    k_prep_rule<<<1024, 256, 0, stream>>>(nbr, rule, cntTab);

    k_conv_sp<<<1024, 512, 0, stream>>>(featb, wbt, rule, cntTab, y1, stats);
    k_bnact<<<8192, 256, 0, stream>>>(y1, stats, g1, b1, y1, 0.05f);

    k_conv_sp<<<1024, 512, 0, stream>>>(y1, wbt + (size_t)27 * 16384, rule, cntTab, y2, stats + 256);
    k_bnact<<<8192, 256, 0, stream>>>(y2, stats + 256, g2, b2, y2, 0.05f);

    k_conv_sp<<<1024, 512, 0, stream>>>(y2, wbt + (size_t)54 * 16384, rule, cntTab, y3, stats + 512);
    k_final<<<8192, 256, 0, stream>>>(y3, stats + 512, g3, b3, y1, (float*)d_out);
}

// Round 3
// 887.061 us; speedup vs baseline: 1.0295x; 1.0295x over previous
//
#include <hip/hip_runtime.h>
#include <hip/hip_bf16.h>
#include <stdint.h>

#define NVOX 131072
#define CCH  128
#define EPSV 1e-4f

typedef __bf16 bf16_t;
typedef bf16_t bf16x8 __attribute__((ext_vector_type(8)));
typedef bf16_t bf16x4 __attribute__((ext_vector_type(4)));
typedef float  f32x4  __attribute__((ext_vector_type(4)));

__device__ __forceinline__ void async16(void* lds, const void* g) {
    __builtin_amdgcn_global_load_lds(
        (const __attribute__((address_space(1))) uint32_t*)g,
        (__attribute__((address_space(3))) uint32_t*)lds, 16, 0, 0);
}

// swizzled f32 accumulator index: breaks the row*128 bank alignment
__device__ __forceinline__ int accIdx(int row, int col) {
    return (row << 7) + ((((col >> 2) + row) & 31) << 2) + (col & 3);
}

// ---------- prep: features f32 -> bf16 ----------
__global__ void k_prep_feat(const float* __restrict__ f, bf16_t* __restrict__ fb) {
    int i = blockIdx.x * 256 + threadIdx.x;      // over N*C/4 = 4194304
    const float4* f4 = (const float4*)f;
    float4 v = f4[i];
    bf16x4 o;
    o[0] = (bf16_t)v.x; o[1] = (bf16_t)v.y; o[2] = (bf16_t)v.z; o[3] = (bf16_t)v.w;
    ((bf16x4*)fb)[i] = o;
}

// ---------- prep: zero pad rows + stats ----------
__global__ void k_prep_misc(bf16_t* featb, bf16_t* y1, bf16_t* y2, float* stats) {
    int t = threadIdx.x;
    if (t < 128) {
        featb[(size_t)NVOX * CCH + t] = (bf16_t)0.0f;
        y1[(size_t)NVOX * CCH + t]    = (bf16_t)0.0f;
        y2[(size_t)NVOX * CCH + t]    = (bf16_t)0.0f;
    }
    for (int i = t; i < 768; i += 256) stats[i] = 0.0f;
}

// ---------- prep: W [27,Ci,Co] f32 -> W^T [layer][k][co][ci] bf16 ----------
__global__ void k_prep_w(const float* __restrict__ w0, const float* __restrict__ w1,
                         const float* __restrict__ w2, bf16_t* __restrict__ wbt) {
    int blk = blockIdx.x;                // 0..80
    int layer = blk / 27, k = blk % 27;
    const float* w = (layer == 0 ? w0 : (layer == 1 ? w1 : w2)) + k * 16384;
    __shared__ bf16_t tile[128][132];
    for (int e = threadIdx.x; e < 16384; e += 256) {
        int ci = e >> 7, co = e & 127;
        tile[co][ci] = (bf16_t)w[e];
    }
    __syncthreads();
    bf16_t* out = wbt + (size_t)blk * 16384;
    for (int e = threadIdx.x; e < 16384; e += 256) {
        int co = e >> 7, ci = e & 127;
        out[e] = tile[co][ci];
    }
}

// ---------- prep: rulebook per (block of 128 rows, tap k) ----------
// entry = (local_row << 18) | gather_idx ; pad entries = NVOX (zero row)
__global__ void k_prep_rule(const int* __restrict__ nbr, unsigned* __restrict__ rule,
                            int* __restrict__ cntTab) {
    __shared__ int snbr[128 * 27];       // 13.5KB
    __shared__ int c0s[4];
    const int b = blockIdx.x, tid = threadIdx.x, m0 = b << 7;
    for (int i = tid; i < 128 * 27; i += 256) snbr[i] = nbr[(size_t)m0 * 27 + i];
    __syncthreads();
    const int w = tid >> 6, l = tid & 63;
    for (int k = 0; k < 27; ++k) {
        int idx = 0; bool valid = false;
        if (tid < 128) { idx = snbr[tid * 27 + k]; valid = idx >= 0; }
        unsigned long long m = __ballot(valid);
        if (l == 0) c0s[w] = (int)__popcll(m);
        __syncthreads();
        int base = (w == 1) ? c0s[0] : 0;
        int total = c0s[0] + c0s[1];
        int prefix = (int)__popcll(m & ((1ull << l) - 1ull));
        unsigned* rk = rule + ((size_t)b * 27 + k) * 128;
        if (valid) rk[base + prefix] = ((unsigned)tid << 18) | (unsigned)idx;
        int nr = ((total + 15) >> 4) << 4;
        if (tid < nr - total) rk[total + tid] = (unsigned)NVOX;   // pad
        if (tid == 0) cntTab[b * 27 + k] = total;
        __syncthreads();
    }
}

// ---------- staging for one pass (B if tap changed, + up to 32 A rows) ----------
__device__ __forceinline__ void stage_pass(
        unsigned e, int p, int tid, int w,
        const char* xb, const char* wbase, const unsigned* ruleB,
        const int* cntLds, bf16_t* smB0, bf16_t* smB1,
        bf16_t* smA0, bf16_t* smA1, unsigned short* rowL0, unsigned short* rowL1)
{
    const int k  = e & 31;
    const int r0 = ((e >> 5) & 3) << 5;
    const int ap = p & 1;
    if (e & 128) {                       // stage B_k (32KB) into parity (e>>8)&1
        char* db = (char*)(((e >> 8) & 1) ? smB1 : smB0);
        const char* wk = wbase + ((size_t)k << 15);
        #pragma unroll
        for (int r = 0; r < 4; ++r) {
            int c = (r << 9) + tid;
            int row = c >> 4, s = c & 15;
            int sg = s ^ (row & 15);
            async16(db + ((size_t)c << 4), wk + (row << 8) + (sg << 4));
        }
    }
    int cnt = cntLds[k];
    int nrows = cnt - r0; if (nrows > 32) nrows = 32;
    int ntiles = (nrows + 15) >> 4;
    int nchunks = ntiles << 8;           // 256 or 512
    const unsigned* rk = ruleB + (k << 7) + r0;
    if ((w << 6) < nchunks) {            // wave-uniform guard
        char* da = (char*)(ap ? smA1 : smA0);
        unsigned short* rl = ap ? rowL1 : rowL0;
        int c = tid;
        int row = c >> 4, s = c & 15;
        unsigned en = rk[row];
        unsigned gidx = en & 0x3FFFFu;
        int sg = s ^ (row & 15);
        async16(da + ((size_t)c << 4), xb + ((size_t)gidx << 8) + (sg << 4));
        if (s == 0) rl[row] = (unsigned short)(en >> 18);
    }
}

// ---------- sparse conv: pipelined rulebook gather-GEMM ----------
__global__ __launch_bounds__(512, 1) void k_conv_sp(
        const bf16_t* __restrict__ xin,     // (N+1) x 128 bf16
        const bf16_t* __restrict__ wbt,     // 27 x 128co x 128ci bf16
        const unsigned* __restrict__ rule,  // [1024][27][128]
        const int* __restrict__ cntTab,     // [1024][27]
        bf16_t* __restrict__ yout,          // N x 128 bf16
        float* __restrict__ stat)           // [0..127]=sum [128..255]=sumsq
{
    __shared__ __align__(16) float  accf[128 * 128];      // 64KB swizzled
    __shared__ __align__(16) bf16_t smB[2][128 * 128];    // 2 x 32KB
    __shared__ __align__(16) bf16_t smA[2][32 * 128];     // 2 x 8KB
    __shared__ unsigned short rowLds[2][32];
    __shared__ unsigned short passLds[128];
    __shared__ int cntLds[27];
    __shared__ int nPassS;
    __shared__ float ssum[128], ssq[128];

    const int tid = threadIdx.x;
    const int b = blockIdx.x;
    const int w = tid >> 6, l = tid & 63;
    const int lrow = l & 15, lq = l >> 4;

    for (int i = tid; i < 128 * 128 / 4; i += 512)
        ((f32x4*)accf)[i] = (f32x4){0.f, 0.f, 0.f, 0.f};
    if (tid < 128) { ssum[tid] = 0.f; ssq[tid] = 0.f; }
    if (tid < 27) cntLds[tid] = cntTab[b * 27 + tid];
    __syncthreads();

    if (tid == 0) {
        int P = 0, bp = 0;
        for (int k = 0; k < 27; ++k) {
            int cnt = cntLds[k];
            for (int r0 = 0; r0 < cnt; r0 += 32) {
                int st = (r0 == 0) ? 1 : 0;
                if (st) bp ^= 1;
                passLds[P++] = (unsigned short)(k | ((r0 >> 5) << 5) | (st << 7) | (bp << 8));
            }
        }
        nPassS = P;
    }
    __syncthreads();
    const int P = nPassS;

    const char* xb = (const char*)xin;
    const char* wbase = (const char*)wbt;
    const unsigned* ruleB = rule + (size_t)b * 27 * 128;

    stage_pass(passLds[0], 0, tid, w, xb, wbase, ruleB, cntLds,
               smB[0], smB[1], smA[0], smA[1], rowLds[0], rowLds[1]);

    for (int p = 0; p < P; ++p) {
        __syncthreads();                  // completes stage(p)
        if (p + 1 < P)
            stage_pass(passLds[p + 1], p + 1, tid, w, xb, wbase, ruleB, cntLds,
                       smB[0], smB[1], smA[0], smA[1], rowLds[0], rowLds[1]);

        // ---- compute pass p ----
        const unsigned e = passLds[p];
        const int k = e & 31;
        const int r0 = ((e >> 5) & 3) << 5;
        const int ap = p & 1, bp = (e >> 8) & 1;
        int cnt = cntLds[k];
        int nrows = cnt - r0; if (nrows > 32) nrows = 32;
        const int ntiles = (nrows + 15) >> 4;

        const char* sb = (const char*)smB[bp];
        const char* sa = (const char*)(ap ? smA[1] : smA[0]);
        const unsigned short* rl = ap ? rowLds[1] : rowLds[0];

        bf16x8 bfr[4];
        #pragma unroll
        for (int c = 0; c < 4; ++c) {
            int slot = ((c << 2) + lq) ^ lrow;
            bfr[c] = *(const bf16x8*)(sb + (((w << 4) + lrow) << 8) + (slot << 4));
        }
        f32x4 tacc[2];
        #pragma unroll
        for (int t = 0; t < 2; ++t) {
            if (t < ntiles) {
                f32x4 a = {0.f, 0.f, 0.f, 0.f};
                #pragma unroll
                for (int c = 0; c < 4; ++c) {
                    int slot = ((c << 2) + lq) ^ lrow;
                    bf16x8 af = *(const bf16x8*)(sa + (((t << 4) + lrow) << 8) + (slot << 4));
                    a = __builtin_amdgcn_mfma_f32_16x16x32_bf16(af, bfr[c], a, 0, 0, 0);
                }
                tacc[t] = a;
            }
        }
        const int col = (w << 4) + lrow;
        #pragma unroll
        for (int t = 0; t < 2; ++t) {
            if (t < ntiles) {
                #pragma unroll
                for (int r = 0; r < 4; ++r) {
                    int ridx = (t << 4) + (lq << 2) + r;
                    if (ridx < nrows) {
                        int row = rl[ridx];
                        accf[accIdx(row, col)] += tacc[t][r];
                    }
                }
            }
        }
    }
    __syncthreads();

    // epilogue: bf16 store + channel stats
    float ps[8] = {0,0,0,0,0,0,0,0}, pq[8] = {0,0,0,0,0,0,0,0};
    const int cb = (tid & 15) << 3;
    bf16_t* yrow = yout + ((size_t)b << 7) * CCH;
    #pragma unroll
    for (int r = 0; r < 4; ++r) {
        int row = (r << 5) + (tid >> 4);
        bf16x8 o;
        #pragma unroll
        for (int i = 0; i < 8; ++i) {
            float v = accf[accIdx(row, cb + i)];
            o[i] = (bf16_t)v;
            ps[i] += v; pq[i] += v * v;
        }
        ((bf16x8*)yrow)[(row << 4) + (tid & 15)] = o;
    }
    #pragma unroll
    for (int i = 0; i < 8; ++i) {
        ps[i] += __shfl_xor(ps[i], 16, 64);
        ps[i] += __shfl_xor(ps[i], 32, 64);
        pq[i] += __shfl_xor(pq[i], 16, 64);
        pq[i] += __shfl_xor(pq[i], 32, 64);
    }
    if (lq == 0) {
        #pragma unroll
        for (int i = 0; i < 8; ++i) {
            atomicAdd(&ssum[cb + i], ps[i]);
            atomicAdd(&ssq[cb + i],  pq[i]);
        }
    }
    __syncthreads();
    if (tid < 128) {
        atomicAdd(&stat[tid],       ssum[tid]);
        atomicAdd(&stat[128 + tid], ssq[tid]);
    }
}

// ---------- BN + LeakyReLU, bf16 in -> bf16 out (in-place safe) ----------
__global__ void k_bnact(const bf16_t* __restrict__ x, const float* __restrict__ stat,
                        const float* __restrict__ g, const float* __restrict__ b,
                        bf16_t* __restrict__ out, float slope) {
    __shared__ float sc[128], sh[128];
    int tid = threadIdx.x;
    if (tid < 128) {
        float mu  = stat[tid] * (1.0f / NVOX);
        float var = stat[128 + tid] * (1.0f / NVOX) - mu * mu;
        float inv = rsqrtf(var + EPSV);
        float s = g[tid] * inv;
        sc[tid] = s;
        sh[tid] = b[tid] - mu * s;
    }
    __syncthreads();
    int i = blockIdx.x * 256 + tid;              // over N*C/8 = 2097152
    bf16x8 v = ((const bf16x8*)x)[i];
    int c = (i << 3) & 127;
    bf16x8 o;
    #pragma unroll
    for (int j = 0; j < 8; ++j) {
        float y = (float)v[j] * sc[c + j] + sh[c + j];
        y = y >= 0.0f ? y : slope * y;
        o[j] = (bf16_t)y;
    }
    ((bf16x8*)out)[i] = o;
}

// ---------- BN3 + residual + LeakyReLU(1/3) -> f32 d_out ----------
__global__ void k_final(const bf16_t* __restrict__ x, const float* __restrict__ stat,
                        const float* __restrict__ g, const float* __restrict__ b,
                        const bf16_t* __restrict__ res, float* __restrict__ out) {
    __shared__ float sc[128], sh[128];
    int tid = threadIdx.x;
    if (tid < 128) {
        float mu  = stat[tid] * (1.0f / NVOX);
        float var = stat[128 + tid] * (1.0f / NVOX) - mu * mu;
        float inv = rsqrtf(var + EPSV);
        float s = g[tid] * inv;
        sc[tid] = s;
        sh[tid] = b[tid] - mu * s;
    }
    __syncthreads();
    int i = blockIdx.x * 256 + tid;              // over N*C/8
    bf16x8 v = ((const bf16x8*)x)[i];
    bf16x8 r8 = ((const bf16x8*)res)[i];
    int c = (i << 3) & 127;
    const float k3 = 1.0f / 3.0f;
    float4 o0, o1;
    #pragma unroll
    for (int j = 0; j < 8; ++j) {
        float y = (float)v[j] * sc[c + j] + sh[c + j] + (float)r8[j];
        y = y >= 0.0f ? y : k3 * y;
        if (j < 4) ((float*)&o0)[j] = y; else ((float*)&o1)[j - 4] = y;
    }
    ((float4*)out)[2 * i]     = o0;
    ((float4*)out)[2 * i + 1] = o1;
}

extern "C" void kernel_launch(void* const* d_in, const int* in_sizes, int n_in,
                              void* d_out, int out_size, void* d_ws, size_t ws_size,
                              hipStream_t stream) {
    (void)in_sizes; (void)n_in; (void)out_size; (void)ws_size;
    const float* features = (const float*)d_in[0];
    const int*   nbr      = (const int*)d_in[1];
    const float* w1 = (const float*)d_in[2];
    const float* w2 = (const float*)d_in[3];
    const float* w3 = (const float*)d_in[4];
    const float* g1 = (const float*)d_in[5];
    const float* b1 = (const float*)d_in[6];
    const float* g2 = (const float*)d_in[7];
    const float* b2 = (const float*)d_in[8];
    const float* g3 = (const float*)d_in[9];
    const float* b3 = (const float*)d_in[10];

    char* ws = (char*)d_ws;
    const size_t SZ_FB = (size_t)(NVOX + 1) * CCH * 2;   // 33,554,688 B
    bf16_t*   featb  = (bf16_t*)(ws);
    bf16_t*   y1     = (bf16_t*)(ws + SZ_FB);
    bf16_t*   y2     = (bf16_t*)(ws + 2 * SZ_FB);
    bf16_t*   y3     = (bf16_t*)(ws + 3 * SZ_FB);
    bf16_t*   wbt    = (bf16_t*)(ws + 4 * SZ_FB);
    unsigned* rule   = (unsigned*)(ws + 4 * SZ_FB + 2654208);
    int*      cntTab = (int*)(ws + 4 * SZ_FB + 2654208 + 14155776);
    float*    stats  = (float*)(ws + 4 * SZ_FB + 2654208 + 14155776 + 110592);

    k_prep_feat<<<16384, 256, 0, stream>>>(features, featb);
    k_prep_misc<<<1, 256, 0, stream>>>(featb, y1, y2, stats);
    k_prep_w<<<81, 256, 0, stream>>>(w1, w2, w3, wbt);
    k_prep_rule<<<1024, 256, 0, stream>>>(nbr, rule, cntTab);

    k_conv_sp<<<1024, 512, 0, stream>>>(featb, wbt, rule, cntTab, y1, stats);
    k_bnact<<<8192, 256, 0, stream>>>(y1, stats, g1, b1, y1, 0.05f);

    k_conv_sp<<<1024, 512, 0, stream>>>(y1, wbt + (size_t)27 * 16384, rule, cntTab, y2, stats + 256);
    k_bnact<<<8192, 256, 0, stream>>>(y2, stats + 256, g2, b2, y2, 0.05f);

    k_conv_sp<<<1024, 512, 0, stream>>>(y2, wbt + (size_t)54 * 16384, rule, cntTab, y3, stats + 512);
    k_final<<<8192, 256, 0, stream>>>(y3, stats + 512, g3, b3, y1, (float*)d_out);
}